// Round 6
// baseline (244.060 us; speedup 1.0000x reference)
//
#include <hip/hip_runtime.h>
#include <hip/hip_bf16.h>
#include <stdint.h>

typedef __bf16 bf16x8 __attribute__((ext_vector_type(8)));
typedef float  f32x4  __attribute__((ext_vector_type(4)));
typedef unsigned short ushort8 __attribute__((ext_vector_type(8)));

#define DEVI static __device__ __forceinline__

static constexpr int TB  = 2;     // batch
static constexpr int TT  = 2048;  // seq len
static constexpr int TC  = 1024;  // d_model
static constexpr int TH  = 16;    // heads
static constexpr int THD = 64;    // head dim
static constexpr int TM  = TB * TT;  // 4096 flattened rows

DEVI unsigned short f2bu(float f) {
  union { float f; unsigned u; } v; v.f = f;
  unsigned u = v.u;
  return (unsigned short)((u + 0x7FFFu + ((u >> 16) & 1u)) >> 16);
}

DEVI void gload_lds16(const unsigned short* g, char* l) {
  __builtin_amdgcn_global_load_lds((const __attribute__((address_space(1))) void*)g,
                                   (__attribute__((address_space(3))) void*)l, 16, 0, 0);
}

// ---------------- cast fp32 -> bf16 (8 elems/thread) ----------------
__global__ void cast_bf16_kernel(const float* __restrict__ in, unsigned short* __restrict__ out, int n8) {
  int i = blockIdx.x * blockDim.x + threadIdx.x;
  if (i >= n8) return;
  float4 a = ((const float4*)in)[2 * i];
  float4 b = ((const float4*)in)[2 * i + 1];
  ushort8 r;
  r[0] = f2bu(a.x); r[1] = f2bu(a.y); r[2] = f2bu(a.z); r[3] = f2bu(a.w);
  r[4] = f2bu(b.x); r[5] = f2bu(b.y); r[6] = f2bu(b.z); r[7] = f2bu(b.w);
  ((ushort8*)out)[i] = r;
}

// ------------- transpose + cast: in fp32 [R][Cc] -> out bf16 [Cc][R] -------------
__global__ void transpose_cast_kernel(const float* __restrict__ in, unsigned short* __restrict__ out,
                                      int R, int Cc) {
  __shared__ float tile[32][33];
  const int c0 = blockIdx.x * 32, r0 = blockIdx.y * 32;
  const int tx = threadIdx.x, ty = threadIdx.y;  // (32, 8)
#pragma unroll
  for (int i = 0; i < 4; ++i)
    tile[ty + i * 8][tx] = in[(size_t)(r0 + ty + i * 8) * Cc + c0 + tx];
  __syncthreads();
#pragma unroll
  for (int i = 0; i < 4; ++i)
    out[(size_t)(c0 + ty + i * 8) * R + r0 + tx] = f2bu(tile[tx][ty + i * 8]);
}

// ------------- per-head V transpose: Vh[b][h][t][d] -> Vt[b][h][d][t] (bf16) -------------
__global__ void transpose_v_kernel(const unsigned short* __restrict__ Vh, unsigned short* __restrict__ Vt) {
  __shared__ unsigned short tile[64][72];  // 64 t-rows x 64 d-cols, padded row (144B)
  const int t0 = blockIdx.x * 64;
  const size_t ho = (size_t)(blockIdx.z * TH + blockIdx.y) * TT * THD;
  const int tid = threadIdx.x;  // 256
#pragma unroll
  for (int it = 0; it < 2; ++it) {
    const int r = it * 32 + (tid >> 3), c8 = tid & 7;
    *(ushort8*)&tile[r][c8 * 8] = *(const ushort8*)(Vh + ho + (size_t)(t0 + r) * THD + c8 * 8);
  }
  __syncthreads();
  const int d = tid >> 2, tc = tid & 3;
  ushort8 a, b;
#pragma unroll
  for (int j = 0; j < 8; ++j) a[j] = tile[tc * 16 + j][d];
#pragma unroll
  for (int j = 0; j < 8; ++j) b[j] = tile[tc * 16 + 8 + j][d];
  *(ushort8*)(Vt + ho + (size_t)d * TT + t0 + tc * 16) = a;
  *(ushort8*)(Vt + ho + (size_t)d * TT + t0 + tc * 16 + 8) = b;
}

// ---------------- GEMM: A[M][K] @ Bt[N][K]^T, bf16 MFMA, 128x128 tile ----------------
// EPI==0: write fp32 C[M][N].  EPI==1: scatter qkv -> per-head Q(,*0.125)/K/V [b][h][t][d].
template <int EPI>
__launch_bounds__(256)
__global__ void gemm_bt_kernel(const unsigned short* __restrict__ A, const unsigned short* __restrict__ Bt,
                               float* __restrict__ Cf,
                               unsigned short* __restrict__ Qo, unsigned short* __restrict__ Ko,
                               unsigned short* __restrict__ Vo,
                               int Mm, int Nn, int Kk) {
  __shared__ __align__(16) char smem[32768];
  char* ldsA = smem;
  char* ldsB = smem + 16384;
  const int tid = threadIdx.x;
  const int lane = tid & 63;
  const int wave = tid >> 6;
  const int l15 = lane & 15, l4 = lane >> 4;
  const int m0 = blockIdx.y * 128;
  const int n0 = blockIdx.x * 128;
  const int wm = (wave >> 1) * 64;
  const int wn = (wave & 1) * 64;

  f32x4 acc[4][4];
#pragma unroll
  for (int a = 0; a < 4; ++a)
#pragma unroll
    for (int b = 0; b < 4; ++b) acc[a][b] = (f32x4){0.f, 0.f, 0.f, 0.f};

  const int nk = Kk >> 6;
  for (int kt = 0; kt < nk; ++kt) {
    __syncthreads();  // previous tile fully consumed
#pragma unroll
    for (int r = 0; r < 4; ++r) {
      // LDS chunk cid holds global k-chunk (cid&7)^(row&7)  (XOR swizzle via pre-permuted source)
      const int cid = r * 256 + tid;
      const int row = cid >> 3;
      const int srcc = (cid & 7) ^ (row & 7);
      gload_lds16(A + (size_t)(m0 + row) * Kk + kt * 64 + srcc * 8, ldsA + (r * 256 + wave * 64) * 16);
      gload_lds16(Bt + (size_t)(n0 + row) * Kk + kt * 64 + srcc * 8, ldsB + (r * 256 + wave * 64) * 16);
    }
    __syncthreads();  // drains vmcnt -> tiles resident
#pragma unroll
    for (int ks = 0; ks < 2; ++ks) {
      bf16x8 af[4], bfv[4];
#pragma unroll
      for (int mf = 0; mf < 4; ++mf) {
        const int row = wm + mf * 16 + l15;
        const int ch = (ks * 4 + l4) ^ (row & 7);
        af[mf] = *(const bf16x8*)(ldsA + row * 128 + ch * 16);
      }
#pragma unroll
      for (int nf = 0; nf < 4; ++nf) {
        const int row = wn + nf * 16 + l15;
        const int ch = (ks * 4 + l4) ^ (row & 7);
        bfv[nf] = *(const bf16x8*)(ldsB + row * 128 + ch * 16);
      }
#pragma unroll
      for (int mf = 0; mf < 4; ++mf)
#pragma unroll
        for (int nf = 0; nf < 4; ++nf)
          acc[mf][nf] = __builtin_amdgcn_mfma_f32_16x16x32_bf16(af[mf], bfv[nf], acc[mf][nf], 0, 0, 0);
    }
  }

  if constexpr (EPI == 0) {
#pragma unroll
    for (int mf = 0; mf < 4; ++mf)
#pragma unroll
      for (int nf = 0; nf < 4; ++nf)
#pragma unroll
        for (int i = 0; i < 4; ++i) {
          const int row = m0 + wm + mf * 16 + l4 * 4 + i;  // D: row=(l>>4)*4+i, col=l&15
          const int col = n0 + wn + nf * 16 + l15;
          Cf[(size_t)row * Nn + col] = acc[mf][nf][i];
        }
  } else {
#pragma unroll
    for (int mf = 0; mf < 4; ++mf)
#pragma unroll
      for (int nf = 0; nf < 4; ++nf)
#pragma unroll
        for (int i = 0; i < 4; ++i) {
          const int row = m0 + wm + mf * 16 + l4 * 4 + i;  // 0..4095
          const int col = n0 + wn + nf * 16 + l15;         // 0..3071
          const int sel = col >> 10;
          const int wi = col & 1023;
          const int h = wi >> 6;
          const int d = wi & 63;
          const int b = row >> 11;
          const int t = row & 2047;
          float v = acc[mf][nf][i];
          if (sel == 0) v *= 0.125f;  // 1/sqrt(64), exact in bf16
          unsigned short* dst = (sel == 0) ? Qo : (sel == 1) ? Ko : Vo;
          dst[((size_t)(b * TH + h) * TT + t) * THD + d] = f2bu(v);
        }
  }
}

// ---------------- flash attention: block = (b, h, heavy/light q-tile pair), 4 waves ----------------
// Waves 0,1 own heavy q-tile qA (64 rows); waves 2,3 own light q-tile qB=31-qA.
// KVBLK=128: each staged buffer holds 128 kv (K[128][64] + V^T[64][128], chunk-XOR swizzled);
// inner body runs twice (two 64-kv online-softmax sub-steps) per barrier pair -> half the syncs.
// Per-CU staged slots = 25, constant (pairing). Double-buffered, counted vmcnt, raw s_barrier.
__launch_bounds__(256)
__global__ void attn_kernel(const unsigned short* __restrict__ Qp, const unsigned short* __restrict__ Kp,
                            const unsigned short* __restrict__ Vt, unsigned short* __restrict__ Op) {
  __shared__ __align__(16) char smem[81920];
  // buf c (c=0,1) at c*32768: K [128 kv][64 d] (128B rows, chunk^(row&7));
  //                          V at +16384: [64 d][128 kv] (256B rows, chunk16 (c&8)|((c^row)&7))
  const int tid = threadIdx.x;   // 256 threads
  const int lane = tid & 63;
  const int wave = tid >> 6;
  char* ldsP = smem + 65536 + wave * 4096;  // per-wave P [32][64] bf16, swizzled
  const int l15 = lane & 15, l4 = lane >> 4;

  const int h = blockIdx.y;
  const int b = blockIdx.z;
  // bxe^15 on half the grid -> each CU's two resident blocks have qA1+qA2 = 47 (balanced staging)
  const int bxe = (int)blockIdx.x ^ (b ? 15 : 0);
  const int qA = 31 - bxe;       // heavy q-tile (16..31)
  const int qB = bxe;            // light q-tile (= 31 - qA)
  const size_t headoff = (size_t)(b * TH + h) * TT * THD;
  const int qt = (wave >> 1) ? qB : qA;
  const int q0 = qt * 64 + (wave & 1) * 32;
  const int ntile = (qA + 2) >> 1;  // 128-kv tiles covering the heavy member's causal range

  // Q fragments in registers (A-operand: lane holds Q[q0+mf*16+l15][ks*32 + l4*8 + j])
  bf16x8 aq[2][2];
#pragma unroll
  for (int mf = 0; mf < 2; ++mf)
#pragma unroll
    for (int ks = 0; ks < 2; ++ks)
      aq[mf][ks] = *(const bf16x8*)(Qp + headoff + (size_t)(q0 + mf * 16 + l15) * THD + ks * 32 + l4 * 8);

  f32x4 o[2][4];
  float mrun[2][4], lrun[2][4];
#pragma unroll
  for (int mf = 0; mf < 2; ++mf) {
#pragma unroll
    for (int nd = 0; nd < 4; ++nd) o[mf][nd] = (f32x4){0.f, 0.f, 0.f, 0.f};
#pragma unroll
    for (int i = 0; i < 4; ++i) { mrun[mf][i] = -3.0e38f; lrun[mf][i] = 0.f; }
  }

  // stage 128-kv tile kt into buffer c: 8 global_load_lds per thread (4 K + 4 V chunks)
  auto stage = [&](int kt, int c) {
    const int kv0 = kt * 128;
    char* bK = smem + c * 32768;
    char* bV = bK + 16384;
#pragma unroll
    for (int r = 0; r < 4; ++r) {
      const int cid = r * 256 + tid;          // 0..1023 chunk id
      const int krow = cid >> 3;              // 0..127 kv
      const int kcol = (cid & 7) ^ (krow & 7);
      gload_lds16(Kp + headoff + (size_t)(kv0 + krow) * THD + kcol * 8, bK + (r * 256 + wave * 64) * 16);
      const int vrow = cid >> 4;              // 0..63 d
      const int vcol = (cid & 8) | ((cid ^ vrow) & 7);
      gload_lds16(Vt + headoff + (size_t)vrow * TT + kv0 + vcol * 8, bV + (r * 256 + wave * 64) * 16);
    }
  };

  int cur = 0;
  stage(0, 0);
  for (int kt = 0; kt < ntile; ++kt) {
    // invariant: tile kt's 8 loads (into buf cur) issued; all waves done reading buf cur^1
    if (kt + 1 < ntile) {
      stage(kt + 1, cur ^ 1);
      asm volatile("s_waitcnt vmcnt(8)" ::: "memory");  // kt's 8 loads retired; prefetch in flight
    } else {
      asm volatile("s_waitcnt vmcnt(0)" ::: "memory");
    }
    __builtin_amdgcn_s_barrier();       // all waves' kt loads visible in LDS
    __builtin_amdgcn_sched_barrier(0);  // pin: no LDS reads hoisted above the barrier
    char* bK = smem + cur * 32768;
    char* bV = bK + 16384;

#pragma unroll
    for (int sub = 0; sub < 2; ++sub) {
      const int kvb = kt * 128 + sub * 64;
      if (kvb <= q0 + 31) {  // wave-uniform: skip sub-tiles beyond this wave's causal range
        // S = Q K^T  (B-operand from K rows: lane holds K[sub*64+nf*16+l15][k-chunk l4])
        f32x4 s[2][4];
#pragma unroll
        for (int mf = 0; mf < 2; ++mf)
#pragma unroll
          for (int nf = 0; nf < 4; ++nf) s[mf][nf] = (f32x4){0.f, 0.f, 0.f, 0.f};
#pragma unroll
        for (int ks = 0; ks < 2; ++ks) {
          bf16x8 bk[4];
#pragma unroll
          for (int nf = 0; nf < 4; ++nf) {
            const int row = sub * 64 + nf * 16 + l15;
            const int ch = (ks * 4 + l4) ^ (row & 7);
            bk[nf] = *(const bf16x8*)(bK + row * 128 + ch * 16);
          }
          __builtin_amdgcn_s_setprio(1);
#pragma unroll
          for (int mf = 0; mf < 2; ++mf)
#pragma unroll
            for (int nf = 0; nf < 4; ++nf)
              s[mf][nf] = __builtin_amdgcn_mfma_f32_16x16x32_bf16(aq[mf][ks], bk[nf], s[mf][nf], 0, 0, 0);
          __builtin_amdgcn_s_setprio(0);
        }

        if (kvb + 63 > q0) {  // causal mask needed for this sub-tile
#pragma unroll
          for (int mf = 0; mf < 2; ++mf)
#pragma unroll
            for (int nf = 0; nf < 4; ++nf)
#pragma unroll
              for (int i = 0; i < 4; ++i) {
                const int rq = q0 + mf * 16 + l4 * 4 + i;
                const int ck = kvb + nf * 16 + l15;
                if (ck > rq) s[mf][nf][i] = -3.0e38f;
              }
        }

        // online softmax; output row r lives in the 16 consecutive lanes sharing l>>4
        float mt[2][4], alpha[2][4], rs[2][4];
#pragma unroll
        for (int mf = 0; mf < 2; ++mf)
#pragma unroll
          for (int i = 0; i < 4; ++i) {
            float m = fmaxf(fmaxf(s[mf][0][i], s[mf][1][i]), fmaxf(s[mf][2][i], s[mf][3][i]));
#pragma unroll
            for (int d = 1; d < 16; d <<= 1) m = fmaxf(m, __shfl_xor(m, d));
            const float mn = fmaxf(mrun[mf][i], m);
            alpha[mf][i] = __expf(mrun[mf][i] - mn);
            mrun[mf][i] = mn;
            mt[mf][i] = mn;
            rs[mf][i] = 0.f;
          }
#pragma unroll
        for (int mf = 0; mf < 2; ++mf)
#pragma unroll
          for (int nf = 0; nf < 4; ++nf)
#pragma unroll
            for (int i = 0; i < 4; ++i) {
              const float p = __expf(s[mf][nf][i] - mt[mf][i]);
              rs[mf][i] += p;
              const int row = mf * 16 + l4 * 4 + i;
              const int col = nf * 16 + l15;
              *(unsigned short*)(ldsP + row * 128 + (((col >> 3) ^ (row & 7)) << 4) + ((col & 7) << 1)) = f2bu(p);
            }
#pragma unroll
        for (int mf = 0; mf < 2; ++mf)
#pragma unroll
          for (int i = 0; i < 4; ++i) {
#pragma unroll
            for (int d = 1; d < 16; d <<= 1) rs[mf][i] += __shfl_xor(rs[mf][i], d);
            lrun[mf][i] = lrun[mf][i] * alpha[mf][i] + rs[mf][i];
          }
#pragma unroll
        for (int mf = 0; mf < 2; ++mf)
#pragma unroll
          for (int nd = 0; nd < 4; ++nd)
#pragma unroll
            for (int i = 0; i < 4; ++i) o[mf][nd][i] *= alpha[mf][i];

        asm volatile("s_waitcnt lgkmcnt(0)" ::: "memory");  // P stores landed (same-wave buffer)

        // O += P V   (A from P_lds; B from bV rows = V^T rows, 256B rows, chunk16 swizzle)
#pragma unroll
        for (int ks2 = 0; ks2 < 2; ++ks2) {
          bf16x8 pa[2];
#pragma unroll
          for (int mf = 0; mf < 2; ++mf) {
            const int row = mf * 16 + l15;
            const int ch = (ks2 * 4 + l4) ^ (row & 7);
            pa[mf] = *(const bf16x8*)(ldsP + row * 128 + ch * 16);
          }
          __builtin_amdgcn_s_setprio(1);
#pragma unroll
          for (int nf = 0; nf < 4; ++nf) {
            const int vrow = nf * 16 + l15;  // d index
            const int c16 = sub * 8 + ks2 * 4 + l4;
            const int ch = (c16 & 8) | ((c16 ^ vrow) & 7);
            const bf16x8 bv = *(const bf16x8*)(bV + vrow * 256 + ch * 16);  // V[kv=kvb+ks2*32+l4*8+j][d=vrow]
#pragma unroll
            for (int mf = 0; mf < 2; ++mf)
              o[mf][nf] = __builtin_amdgcn_mfma_f32_16x16x32_bf16(pa[mf], bv, o[mf][nf], 0, 0, 0);
          }
          __builtin_amdgcn_s_setprio(0);
        }
      }  // active-sub-tile guard
    }    // sub

    __builtin_amdgcn_s_barrier();  // all waves done reading buf cur -> next iter may prefetch into it
    cur ^= 1;
  }

  // epilogue: O normalized -> [b*T + t][h*64 + d] bf16
#pragma unroll
  for (int mf = 0; mf < 2; ++mf)
#pragma unroll
    for (int nd = 0; nd < 4; ++nd)
#pragma unroll
      for (int i = 0; i < 4; ++i) {
        const int row = q0 + mf * 16 + l4 * 4 + i;
        const int col = h * THD + nd * 16 + l15;
        Op[(size_t)(b * TT + row) * TC + col] = f2bu(o[mf][nd][i] / lrun[mf][i]);
      }
}

extern "C" void kernel_launch(void* const* d_in, const int* in_sizes, int n_in,
                              void* d_out, int out_size, void* d_ws, size_t ws_size,
                              hipStream_t stream) {
  (void)in_sizes; (void)n_in; (void)out_size; (void)ws_size;
  const float* x = (const float*)d_in[0];
  const float* wqkv = (const float*)d_in[1];
  const float* wout = (const float*)d_in[2];
  char* ws = (char*)d_ws;
  unsigned short* Xb = (unsigned short*)(ws);                          // [4096][1024] bf16, 8 MiB
  unsigned short* Wq = (unsigned short*)(ws + ((size_t)8 << 20));      // [3072][1024] bf16, 6 MiB
  unsigned short* Wo = (unsigned short*)(ws + ((size_t)14 << 20));     // [1024][1024] bf16, 2 MiB
  unsigned short* Qh = (unsigned short*)(ws + ((size_t)16 << 20));     // [b][h][t][d] bf16, 8 MiB
  unsigned short* Kh = (unsigned short*)(ws + ((size_t)24 << 20));
  unsigned short* Vh = (unsigned short*)(ws + ((size_t)32 << 20));
  unsigned short* Oh = (unsigned short*)(ws + ((size_t)40 << 20));     // [4096][1024] bf16
  unsigned short* Vtp = Xb;  // Xb slot is dead after the QKV GEMM; reuse for Vt [b][h][d][t]
  float* out = (float*)d_out;

  cast_bf16_kernel<<<2048, 256, 0, stream>>>(x, Xb, TM * TC / 8);
  transpose_cast_kernel<<<dim3(96, 32), dim3(32, 8), 0, stream>>>(wqkv, Wq, TC, 3 * TC);
  transpose_cast_kernel<<<dim3(32, 32), dim3(32, 8), 0, stream>>>(wout, Wo, TC, TC);
  gemm_bt_kernel<1><<<dim3(24, 32), 256, 0, stream>>>(Xb, Wq, nullptr, Qh, Kh, Vh, TM, 3 * TC, TC);
  transpose_v_kernel<<<dim3(32, 16, 2), 256, 0, stream>>>(Vh, Vtp);
  attn_kernel<<<dim3(16, 16, 2), 256, 0, stream>>>(Qh, Kh, Vtp, Oh);
  gemm_bt_kernel<0><<<dim3(8, 32), 256, 0, stream>>>(Oh, Wo, out, nullptr, nullptr, nullptr, TM, TC, TC);
}

// Round 8
// 196.389 us; speedup vs baseline: 1.2427x; 1.2427x over previous
//
#include <hip/hip_runtime.h>
#include <hip/hip_bf16.h>
#include <stdint.h>

typedef __bf16 bf16x8 __attribute__((ext_vector_type(8)));
typedef float  f32x4  __attribute__((ext_vector_type(4)));
typedef float  f32x16 __attribute__((ext_vector_type(16)));
typedef unsigned short ushort8 __attribute__((ext_vector_type(8)));
typedef unsigned short ushort4v __attribute__((ext_vector_type(4)));

#define DEVI static __device__ __forceinline__

static constexpr int TB  = 2;     // batch
static constexpr int TT  = 2048;  // seq len
static constexpr int TC  = 1024;  // d_model
static constexpr int TH  = 16;    // heads
static constexpr int THD = 64;    // head dim
static constexpr int TM  = TB * TT;  // 4096 flattened rows

DEVI unsigned short f2bu(float f) {
  union { float f; unsigned u; } v; v.f = f;
  unsigned u = v.u;
  return (unsigned short)((u + 0x7FFFu + ((u >> 16) & 1u)) >> 16);
}

DEVI unsigned cvtpk(float lo, float hi) {  // packed bf16(lo) | bf16(hi)<<16 (RNE)
  unsigned r;
  asm("v_cvt_pk_bf16_f32 %0, %1, %2" : "=v"(r) : "v"(lo), "v"(hi));
  return r;
}

DEVI void gload_lds16(const unsigned short* g, char* l) {
  __builtin_amdgcn_global_load_lds((const __attribute__((address_space(1))) void*)g,
                                   (__attribute__((address_space(3))) void*)l, 16, 0, 0);
}

// ---------------- cast fp32 -> bf16 (8 elems/thread) ----------------
__global__ void cast_bf16_kernel(const float* __restrict__ in, unsigned short* __restrict__ out, int n8) {
  int i = blockIdx.x * blockDim.x + threadIdx.x;
  if (i >= n8) return;
  float4 a = ((const float4*)in)[2 * i];
  float4 b = ((const float4*)in)[2 * i + 1];
  ushort8 r;
  r[0] = f2bu(a.x); r[1] = f2bu(a.y); r[2] = f2bu(a.z); r[3] = f2bu(a.w);
  r[4] = f2bu(b.x); r[5] = f2bu(b.y); r[6] = f2bu(b.z); r[7] = f2bu(b.w);
  ((ushort8*)out)[i] = r;
}

// ------------- transpose + cast: in fp32 [R][Cc] -> out bf16 [Cc][R] -------------
__global__ void transpose_cast_kernel(const float* __restrict__ in, unsigned short* __restrict__ out,
                                      int R, int Cc) {
  __shared__ float tile[32][33];
  const int c0 = blockIdx.x * 32, r0 = blockIdx.y * 32;
  const int tx = threadIdx.x, ty = threadIdx.y;  // (32, 8)
#pragma unroll
  for (int i = 0; i < 4; ++i)
    tile[ty + i * 8][tx] = in[(size_t)(r0 + ty + i * 8) * Cc + c0 + tx];
  __syncthreads();
#pragma unroll
  for (int i = 0; i < 4; ++i)
    out[(size_t)(c0 + ty + i * 8) * R + r0 + tx] = f2bu(tile[tx][ty + i * 8]);
}

// ------------- per-head V transpose: Vh[b][h][t][d] -> Vt[b][h][d][t] (bf16) -------------
__global__ void transpose_v_kernel(const unsigned short* __restrict__ Vh, unsigned short* __restrict__ Vt) {
  __shared__ unsigned short tile[64][72];  // 64 t-rows x 64 d-cols, padded row (144B)
  const int t0 = blockIdx.x * 64;
  const size_t ho = (size_t)(blockIdx.z * TH + blockIdx.y) * TT * THD;
  const int tid = threadIdx.x;  // 256
#pragma unroll
  for (int it = 0; it < 2; ++it) {
    const int r = it * 32 + (tid >> 3), c8 = tid & 7;
    *(ushort8*)&tile[r][c8 * 8] = *(const ushort8*)(Vh + ho + (size_t)(t0 + r) * THD + c8 * 8);
  }
  __syncthreads();
  const int d = tid >> 2, tc = tid & 3;
  ushort8 a, b;
#pragma unroll
  for (int j = 0; j < 8; ++j) a[j] = tile[tc * 16 + j][d];
#pragma unroll
  for (int j = 0; j < 8; ++j) b[j] = tile[tc * 16 + 8 + j][d];
  *(ushort8*)(Vt + ho + (size_t)d * TT + t0 + tc * 16) = a;
  *(ushort8*)(Vt + ho + (size_t)d * TT + t0 + tc * 16 + 8) = b;
}

// ---------------- GEMM: A[M][K] @ Bt[N][K]^T, bf16 MFMA, 128x128 tile ----------------
// EPI==0: write fp32 C[M][N].  EPI==1: scatter qkv -> per-head Q(,*0.125)/K/V [b][h][t][d].
template <int EPI>
__launch_bounds__(256)
__global__ void gemm_bt_kernel(const unsigned short* __restrict__ A, const unsigned short* __restrict__ Bt,
                               float* __restrict__ Cf,
                               unsigned short* __restrict__ Qo, unsigned short* __restrict__ Ko,
                               unsigned short* __restrict__ Vo,
                               int Mm, int Nn, int Kk) {
  __shared__ __align__(16) char smem[32768];
  char* ldsA = smem;
  char* ldsB = smem + 16384;
  const int tid = threadIdx.x;
  const int lane = tid & 63;
  const int wave = tid >> 6;
  const int l15 = lane & 15, l4 = lane >> 4;
  const int m0 = blockIdx.y * 128;
  const int n0 = blockIdx.x * 128;
  const int wm = (wave >> 1) * 64;
  const int wn = (wave & 1) * 64;

  f32x4 acc[4][4];
#pragma unroll
  for (int a = 0; a < 4; ++a)
#pragma unroll
    for (int b = 0; b < 4; ++b) acc[a][b] = (f32x4){0.f, 0.f, 0.f, 0.f};

  const int nk = Kk >> 6;
  for (int kt = 0; kt < nk; ++kt) {
    __syncthreads();  // previous tile fully consumed
#pragma unroll
    for (int r = 0; r < 4; ++r) {
      // LDS chunk cid holds global k-chunk (cid&7)^(row&7)  (XOR swizzle via pre-permuted source)
      const int cid = r * 256 + tid;
      const int row = cid >> 3;
      const int srcc = (cid & 7) ^ (row & 7);
      gload_lds16(A + (size_t)(m0 + row) * Kk + kt * 64 + srcc * 8, ldsA + (r * 256 + wave * 64) * 16);
      gload_lds16(Bt + (size_t)(n0 + row) * Kk + kt * 64 + srcc * 8, ldsB + (r * 256 + wave * 64) * 16);
    }
    __syncthreads();  // drains vmcnt -> tiles resident
#pragma unroll
    for (int ks = 0; ks < 2; ++ks) {
      bf16x8 af[4], bfv[4];
#pragma unroll
      for (int mf = 0; mf < 4; ++mf) {
        const int row = wm + mf * 16 + l15;
        const int ch = (ks * 4 + l4) ^ (row & 7);
        af[mf] = *(const bf16x8*)(ldsA + row * 128 + ch * 16);
      }
#pragma unroll
      for (int nf = 0; nf < 4; ++nf) {
        const int row = wn + nf * 16 + l15;
        const int ch = (ks * 4 + l4) ^ (row & 7);
        bfv[nf] = *(const bf16x8*)(ldsB + row * 128 + ch * 16);
      }
#pragma unroll
      for (int mf = 0; mf < 4; ++mf)
#pragma unroll
        for (int nf = 0; nf < 4; ++nf)
          acc[mf][nf] = __builtin_amdgcn_mfma_f32_16x16x32_bf16(af[mf], bfv[nf], acc[mf][nf], 0, 0, 0);
    }
  }

  if constexpr (EPI == 0) {
#pragma unroll
    for (int mf = 0; mf < 4; ++mf)
#pragma unroll
      for (int nf = 0; nf < 4; ++nf)
#pragma unroll
        for (int i = 0; i < 4; ++i) {
          const int row = m0 + wm + mf * 16 + l4 * 4 + i;  // D: row=(l>>4)*4+i, col=l&15
          const int col = n0 + wn + nf * 16 + l15;
          Cf[(size_t)row * Nn + col] = acc[mf][nf][i];
        }
  } else {
#pragma unroll
    for (int mf = 0; mf < 4; ++mf)
#pragma unroll
      for (int nf = 0; nf < 4; ++nf)
#pragma unroll
        for (int i = 0; i < 4; ++i) {
          const int row = m0 + wm + mf * 16 + l4 * 4 + i;  // 0..4095
          const int col = n0 + wn + nf * 16 + l15;         // 0..3071
          const int sel = col >> 10;
          const int wi = col & 1023;
          const int h = wi >> 6;
          const int d = wi & 63;
          const int b = row >> 11;
          const int t = row & 2047;
          float v = acc[mf][nf][i];
          if (sel == 0) v *= 0.125f;  // 1/sqrt(64), exact in bf16
          unsigned short* dst = (sel == 0) ? Qo : (sel == 1) ? Ko : Vo;
          dst[((size_t)(b * TH + h) * TT + t) * THD + d] = f2bu(v);
        }
  }
}

// ---------------- flash attention: swapped-QK^T, in-register softmax ----------------
// Block = (b,h, heavy/light q-tile pair), 4 waves; waves 0,1 = heavy qA (64 rows), 2,3 = light qB.
// Per wave: 32 q-rows, one per lane-column (q = q0 + (lane&31)).
// S^T = mfma_32x32x16(K_frag, Q_frag): lane holds P[q][32 kv in regs] (C/D m74/m101 layout).
// Softmax in-register; cross-half reduce via __shfl_xor(,32). PV uses P's NATURAL register
// order as the k-slot convention (slot(hi,j) = (j&3)+8*(j>>2)+4*hi): pb = pairwise cvt_pk of
// sequential s regs (NO cross-lane repack); V^T read slot-matched via 2x ds_read_b64.
// k-slot mapping is shared by A and B on every MFMA -> result invariant to HW's physical k order.
__launch_bounds__(256)
__global__ void attn_kernel(const unsigned short* __restrict__ Qp, const unsigned short* __restrict__ Kp,
                            const unsigned short* __restrict__ Vt, unsigned short* __restrict__ Op) {
  __shared__ __align__(16) char smem[32768];
  // buf c (c=0,1) at c*16384: K [64 kv][64 d] (128B rows, chunk^(row&7));
  //                          V^T at +8192: [64 d][64 kv] (128B rows, same swizzle)
  const int tid = threadIdx.x;   // 256 threads
  const int lane = tid & 63;
  const int wave = tid >> 6;
  const int l31 = lane & 31, hi = lane >> 5;

  const int h = blockIdx.y;
  const int b = blockIdx.z;
  const int bxe = (int)blockIdx.x ^ (b ? 15 : 0);  // de-alias CU assignment across z
  const int qA = 31 - bxe;       // heavy q-tile (16..31)
  const int qB = bxe;            // light q-tile (= 31 - qA)
  const size_t headoff = (size_t)(b * TH + h) * TT * THD;
  const int qt = (wave >> 1) ? qB : qA;
  const int q0 = qt * 64 + (wave & 1) * 32;
  const int ntile = qA + 1;      // 64-kv tiles covering the heavy member's causal range
  const int rq = q0 + l31;       // this lane's q row

  // Q as B-operand: lane slot (hi,j) holds Q[q0+l31][ks*16 + hi*8 + j]
  bf16x8 aq[4];
#pragma unroll
  for (int ks = 0; ks < 4; ++ks)
    aq[ks] = *(const bf16x8*)(Qp + headoff + (size_t)rq * THD + ks * 16 + hi * 8);

  f32x16 o[2];  // O^T accum: o[dt][r] = O[d = dt*32 + (r&3)+8*(r>>2)+4*hi][q = l31]
#pragma unroll
  for (int dt = 0; dt < 2; ++dt)
#pragma unroll
    for (int r = 0; r < 16; ++r) o[dt][r] = 0.f;
  float mrun = -3.0e38f, lrun = 0.f;

  // stage 64-kv tile kt into buffer c: 4 global_load_lds per thread (2 K + 2 V chunks)
  auto stage = [&](int kt, int c) {
    const int kv0 = kt * 64;
    char* bK = smem + c * 16384;
    char* bV = bK + 8192;
#pragma unroll
    for (int r = 0; r < 2; ++r) {
      const int cid = r * 256 + tid;   // 0..511 chunk id
      const int row = cid >> 3;
      const int srcc = (cid & 7) ^ (row & 7);
      gload_lds16(Kp + headoff + (size_t)(kv0 + row) * THD + srcc * 8, bK + (r * 256 + wave * 64) * 16);
      gload_lds16(Vt + headoff + (size_t)row * TT + kv0 + srcc * 8, bV + (r * 256 + wave * 64) * 16);
    }
  };

  int cur = 0;
  stage(0, 0);
  for (int kt = 0; kt < ntile; ++kt) {
    const int kv0 = kt * 64;
    if (kt + 1 < ntile) {
      stage(kt + 1, cur ^ 1);
      asm volatile("s_waitcnt vmcnt(4)" ::: "memory");  // kt's 4 loads retired; prefetch in flight
    } else {
      asm volatile("s_waitcnt vmcnt(0)" ::: "memory");
    }
    __builtin_amdgcn_s_barrier();       // all waves' kt loads visible in LDS
    __builtin_amdgcn_sched_barrier(0);  // no LDS reads hoisted above the barrier
    char* ldsK = smem + cur * 16384;
    char* ldsV = ldsK + 8192;

    if (kv0 <= q0 + 31) {  // wave-uniform: light waves skip tiles beyond their causal range
      // S^T[kv][q] = K x Q^T : A-frag = K rows from LDS, B-frag = Q rows (registers)
      f32x16 s[2];
#pragma unroll
      for (int kvt = 0; kvt < 2; ++kvt) {
#pragma unroll
        for (int r = 0; r < 16; ++r) s[kvt][r] = 0.f;
#pragma unroll
        for (int ks = 0; ks < 4; ++ks) {
          const int row = kvt * 32 + l31;                 // kv row in ldsK
          const int ch = (ks * 2 + hi) ^ (row & 7);
          const bf16x8 ak = *(const bf16x8*)(ldsK + row * 128 + ch * 16);
          s[kvt] = __builtin_amdgcn_mfma_f32_32x32x16_bf16(ak, aq[ks], s[kvt], 0, 0, 0);
        }
      }

      if (kv0 + 63 > q0) {  // causal mask: kv > q -> -inf  (kv = kv0+kvt*32+(r&3)+8*(r>>2)+4*hi)
#pragma unroll
        for (int kvt = 0; kvt < 2; ++kvt)
#pragma unroll
          for (int r = 0; r < 16; ++r) {
            const int ck = kv0 + kvt * 32 + (r & 3) + 8 * (r >> 2) + 4 * hi;
            if (ck > rq) s[kvt][r] = -3.0e38f;
          }
      }

      // in-register online softmax (lane pair l, l+32 shares q-row; halves exchanged via shfl)
      float mx = s[0][0];
#pragma unroll
      for (int kvt = 0; kvt < 2; ++kvt)
#pragma unroll
        for (int r = 0; r < 16; ++r) mx = fmaxf(mx, s[kvt][r]);
      mx = fmaxf(mx, __shfl_xor(mx, 32));
      if (!__all(mx <= mrun + 8.f)) {  // T13 defer-max: rescale only on significant growth
        const float mn = fmaxf(mrun, mx);
        const float al = __expf(mrun - mn);
        lrun *= al;
#pragma unroll
        for (int dt = 0; dt < 2; ++dt)
#pragma unroll
          for (int r = 0; r < 16; ++r) o[dt][r] *= al;
        mrun = mn;
      }
      float rs = 0.f;
#pragma unroll
      for (int kvt = 0; kvt < 2; ++kvt)
#pragma unroll
        for (int r = 0; r < 16; ++r) {
          const float p = __expf(s[kvt][r] - mrun);
          s[kvt][r] = p;
          rs += p;
        }
      lrun += rs + __shfl_xor(rs, 32);

      // P -> PV B-operand in NATURAL register order: pb[n] word w = cvtpk(s[2w], s[2w+1])
      // slot convention slot(hi,j) = (j&3) + 8*(j>>2) + 4*hi, kv = n*16 + slot
      bf16x8 pb[4];
#pragma unroll
      for (int kvt = 0; kvt < 2; ++kvt)
#pragma unroll
        for (int kh = 0; kh < 2; ++kh) {
          union { unsigned u[4]; bf16x8 v; } pk;
#pragma unroll
          for (int w = 0; w < 4; ++w)
            pk.u[w] = cvtpk(s[kvt][kh * 8 + 2 * w], s[kvt][kh * 8 + 2 * w + 1]);
          pb[kvt * 2 + kh] = pk.v;
        }

      // O^T += V^T x P^T : A-frag = V^T rows read slot-matched (2x b64 per fragment)
#pragma unroll
      for (int dt = 0; dt < 2; ++dt)
#pragma unroll
        for (int n = 0; n < 4; ++n) {
          const int row = dt * 32 + l31;                  // d row in ldsV
          const int c1 = (2 * n) ^ (row & 7);
          const int c2 = (2 * n + 1) ^ (row & 7);
          union { ushort4v h[2]; bf16x8 v; } av;
          av.h[0] = *(const ushort4v*)(ldsV + row * 128 + c1 * 16 + hi * 8);  // kv = 16n+4hi+0..3
          av.h[1] = *(const ushort4v*)(ldsV + row * 128 + c2 * 16 + hi * 8);  // kv = 16n+8+4hi+0..3
          o[dt] = __builtin_amdgcn_mfma_f32_32x32x16_bf16(av.v, pb[n], o[dt], 0, 0, 0);
        }
    }  // active-tile guard

    asm volatile("s_waitcnt lgkmcnt(0)" ::: "memory");  // this wave's LDS reads complete
    __builtin_amdgcn_sched_barrier(0);                  // nothing sinks below the fence
    __builtin_amdgcn_s_barrier();  // all waves done reading buf cur -> next iter may prefetch
    cur ^= 1;
  }

  // epilogue: O[q][d] = O^T/lrun -> [b*T + q][h*64 + d] bf16 (4 consecutive d per 8B store)
  const float inv = 1.0f / lrun;
  unsigned short* orow = Op + (size_t)(b * TT + rq) * TC + h * THD;
#pragma unroll
  for (int dt = 0; dt < 2; ++dt)
#pragma unroll
    for (int r4 = 0; r4 < 4; ++r4) {
      const unsigned u0 = cvtpk(o[dt][r4 * 4 + 0] * inv, o[dt][r4 * 4 + 1] * inv);
      const unsigned u1 = cvtpk(o[dt][r4 * 4 + 2] * inv, o[dt][r4 * 4 + 3] * inv);
      uint2 w; w.x = u0; w.y = u1;
      *(uint2*)(orow + dt * 32 + r4 * 8 + hi * 4) = w;   // d = dt*32 + 8*r4 + 4*hi + 0..3
    }
}

extern "C" void kernel_launch(void* const* d_in, const int* in_sizes, int n_in,
                              void* d_out, int out_size, void* d_ws, size_t ws_size,
                              hipStream_t stream) {
  (void)in_sizes; (void)n_in; (void)out_size; (void)ws_size;
  const float* x = (const float*)d_in[0];
  const float* wqkv = (const float*)d_in[1];
  const float* wout = (const float*)d_in[2];
  char* ws = (char*)d_ws;
  unsigned short* Xb = (unsigned short*)(ws);                          // [4096][1024] bf16, 8 MiB
  unsigned short* Wq = (unsigned short*)(ws + ((size_t)8 << 20));      // [3072][1024] bf16, 6 MiB
  unsigned short* Wo = (unsigned short*)(ws + ((size_t)14 << 20));     // [1024][1024] bf16, 2 MiB
  unsigned short* Qh = (unsigned short*)(ws + ((size_t)16 << 20));     // [b][h][t][d] bf16, 8 MiB
  unsigned short* Kh = (unsigned short*)(ws + ((size_t)24 << 20));
  unsigned short* Vh = (unsigned short*)(ws + ((size_t)32 << 20));
  unsigned short* Oh = (unsigned short*)(ws + ((size_t)40 << 20));     // [4096][1024] bf16
  unsigned short* Vtp = Xb;  // Xb slot is dead after the QKV GEMM; reuse for Vt [b][h][d][t]
  float* out = (float*)d_out;

  cast_bf16_kernel<<<2048, 256, 0, stream>>>(x, Xb, TM * TC / 8);
  transpose_cast_kernel<<<dim3(96, 32), dim3(32, 8), 0, stream>>>(wqkv, Wq, TC, 3 * TC);
  transpose_cast_kernel<<<dim3(32, 32), dim3(32, 8), 0, stream>>>(wout, Wo, TC, TC);
  gemm_bt_kernel<1><<<dim3(24, 32), 256, 0, stream>>>(Xb, Wq, nullptr, Qh, Kh, Vh, TM, 3 * TC, TC);
  transpose_v_kernel<<<dim3(32, 16, 2), 256, 0, stream>>>(Vh, Vtp);
  attn_kernel<<<dim3(16, 16, 2), 256, 0, stream>>>(Qh, Kh, Vtp, Oh);
  gemm_bt_kernel<0><<<dim3(8, 32), 256, 0, stream>>>(Oh, Wo, out, nullptr, nullptr, nullptr, TM, TC, TC);
}